// Round 1
// baseline (479.719 us; speedup 1.0000x reference)
//
#include <hip/hip_runtime.h>
#include <float.h>

// FeatPropagation: k=3 NN interpolation.
// Phase A: per-thread query, exhaustive scan of the batch's 4096 source points
//          staged in LDS as float4(x,y,z,s2). d2 replicates the reference's
//          exact fp32 op sequence: d2 = (q2 + s2) - 2*((qx*sx + qy*sy) + qz*sz)
//          with NO fma contraction (__fmul_rn/__fadd_rn) so top-3 selection
//          matches jax.lax.top_k bit-for-bit (ties -> lower index, strict <).
// Phase B: wave-level broadcast of idx/weights via __shfl; lane l covers
//          channels [4l, 4l+4) as float4 -> coalesced gather + store.

#define NPTS 4096   // source points per batch (asserted via sizes)
#define QPB  256    // queries per block == blockDim

__global__ __launch_bounds__(256) void fp_knn_interp(
    const float* __restrict__ xyz,      // [B*N, 3]
    const float* __restrict__ new_xyz,  // [B*M, 3]
    const float* __restrict__ feat,     // [B*N, 256]
    float* __restrict__ out,            // [B*M, 256]
    int N, int groups_per_batch)
{
    __shared__ float4 s_pts[NPTS];  // 64 KiB: (x, y, z, s2)

    int g = blockIdx.x;
    // XCD-aware swizzle (bijective on 0..255): batch b's 64 blocks land on
    // XCD pair {2b, 2b+1} so feat gathers (4 MiB/batch) fit one XCD's L2.
    if (gridDim.x == 256 && groups_per_batch == 64) {
        const int xcd = g & 7, slot = g >> 3;
        g = (xcd >> 1) * 64 + (xcd & 1) * 32 + slot;
    }

    const int tid = threadIdx.x;
    const int b = g / groups_per_batch;
    const int src_base = b * N;

    // ---- stage source points + |s|^2 into LDS ----
    for (int j = tid; j < N; j += QPB) {
        const float sx = xyz[(size_t)(src_base + j) * 3 + 0];
        const float sy = xyz[(size_t)(src_base + j) * 3 + 1];
        const float sz = xyz[(size_t)(src_base + j) * 3 + 2];
        const float s2 = __fadd_rn(__fadd_rn(__fmul_rn(sx, sx), __fmul_rn(sy, sy)),
                                   __fmul_rn(sz, sz));
        s_pts[j] = make_float4(sx, sy, sz, s2);
    }
    __syncthreads();

    // ---- phase A: exhaustive 3-NN for this thread's query ----
    const int m = g * QPB + tid;  // global query index
    const float qx = new_xyz[(size_t)m * 3 + 0];
    const float qy = new_xyz[(size_t)m * 3 + 1];
    const float qz = new_xyz[(size_t)m * 3 + 2];
    const float q2 = __fadd_rn(__fadd_rn(__fmul_rn(qx, qx), __fmul_rn(qy, qy)),
                               __fmul_rn(qz, qz));

    float b0 = FLT_MAX, b1 = FLT_MAX, b2 = FLT_MAX;
    int   i0 = 0, i1 = 0, i2 = 0;

    #pragma unroll 4
    for (int j = 0; j < N; ++j) {
        const float4 p = s_pts[j];  // broadcast read, conflict-free
        const float cross = __fadd_rn(
            __fadd_rn(__fmul_rn(qx, p.x), __fmul_rn(qy, p.y)),
            __fmul_rn(qz, p.z));
        // (q2 + s2) - 2*cross, each op rounded once; 2*cross == cross+cross exact
        const float d2 = __fadd_rn(q2, p.w) - (cross + cross);
        if (d2 < b2) {                       // rare path: wave-level branch
            if (d2 < b0)      { b2 = b1; i2 = i1; b1 = b0; i1 = i0; b0 = d2; i0 = j; }
            else if (d2 < b1) { b2 = b1; i2 = i1; b1 = d2; i1 = j; }
            else              { b2 = d2; i2 = j; }
        }
    }

    // ---- weights (micro-rounding here is far below tolerance) ----
    const float e0 = sqrtf(fmaxf(b0, 1e-12f));
    const float e1 = sqrtf(fmaxf(b1, 1e-12f));
    const float e2 = sqrtf(fmaxf(b2, 1e-12f));
    const float r0 = 1.0f / (e0 + 1e-8f);
    const float r1 = 1.0f / (e1 + 1e-8f);
    const float r2 = 1.0f / (e2 + 1e-8f);
    const float rs = r0 + r1 + r2;
    float w0 = r0 / rs, w1 = r1 / rs, w2 = r2 / rs;

    // ---- phase B: per-wave gather + interpolate, float4 per lane ----
    const float4* __restrict__ feat4 = (const float4*)feat;  // [B*N, 64]
    float4* __restrict__ out4 = (float4*)out;                // [B*M, 64]
    const int lane  = tid & 63;
    const int wv    = tid >> 6;
    const int qbase = g * QPB + wv * 64;  // global query of this wave's lane 0

    for (int s = 0; s < 64; ++s) {
        const int   j0 = __shfl(i0, s);
        const int   j1 = __shfl(i1, s);
        const int   j2 = __shfl(i2, s);
        const float u0 = __shfl(w0, s);
        const float u1 = __shfl(w1, s);
        const float u2 = __shfl(w2, s);
        const float4* f0 = feat4 + (size_t)(src_base + j0) * 64;
        const float4* f1 = feat4 + (size_t)(src_base + j1) * 64;
        const float4* f2 = feat4 + (size_t)(src_base + j2) * 64;
        const float4 a = f0[lane];
        const float4 c = f1[lane];
        const float4 e = f2[lane];
        float4 o;
        o.x = u0 * a.x + u1 * c.x + u2 * e.x;
        o.y = u0 * a.y + u1 * c.y + u2 * e.y;
        o.z = u0 * a.z + u1 * c.z + u2 * e.z;
        o.w = u0 * a.w + u1 * c.w + u2 * e.w;
        out4[(size_t)(qbase + s) * 64 + lane] = o;
    }
}

extern "C" void kernel_launch(void* const* d_in, const int* in_sizes, int n_in,
                              void* d_out, int out_size, void* d_ws, size_t ws_size,
                              hipStream_t stream) {
    const float* xyz     = (const float*)d_in[0];
    const float* new_xyz = (const float*)d_in[1];
    const float* feat    = (const float*)d_in[2];
    float* out = (float*)d_out;

    const int B = in_sizes[3];                 // 4
    const int N = in_sizes[0] / (3 * B);       // 4096
    const int M = in_sizes[1] / (3 * B);       // 16384
    const int groups_per_batch = M / QPB;      // 64
    const int blocks = (B * M) / QPB;          // 256

    fp_knn_interp<<<blocks, QPB, 0, stream>>>(xyz, new_xyz, feat, out,
                                              N, groups_per_batch);
}

// Round 2
// 262.653 us; speedup vs baseline: 1.8264x; 1.8264x over previous
//
#include <hip/hip_runtime.h>
#include <float.h>

// FeatPropagation k=3 NN interpolation, round 2.
// R1 post-mortem: 64KiB LDS stage + grid 256 -> 1 wave/SIMD -> VALUBusy 24%,
// latency-bound at 411 us. Fix: no LDS point staging (points packed as
// float4(x,y,z,s2) in d_ws, wave-uniform L2-resident loads), split-K x4
// (grid 1024, 16 waves/CU), branchless min/med3 top-3 insert.
//
// Exactness contract (absmax threshold 0.074 is 2% of ref absmax; one top-3
// flip = O(0.6) error): d2 = (q2+s2) - 2*cross computed with __fmul_rn/
// __fadd_rn exactly as the reference's op sequence, strict < insertion,
// ascending candidate order, merge ties broken by lower index.

#define QPB   64   // queries per block
#define SPLIT 4    // candidate chunks per block == waves per block

__global__ void pack_pts(const float* __restrict__ xyz,
                         float4* __restrict__ pts, int total) {
    int i = blockIdx.x * blockDim.x + threadIdx.x;
    if (i < total) {
        const float sx = xyz[(size_t)i * 3 + 0];
        const float sy = xyz[(size_t)i * 3 + 1];
        const float sz = xyz[(size_t)i * 3 + 2];
        const float s2 = __fadd_rn(__fadd_rn(__fmul_rn(sx, sx), __fmul_rn(sy, sy)),
                                   __fmul_rn(sz, sz));
        pts[i] = make_float4(sx, sy, sz, s2);
    }
}

template <bool PACKED>
__global__ __launch_bounds__(256, 4) void fp_knn_main(
    const float* __restrict__ new_xyz,   // [B*M, 3]
    const float4* __restrict__ pts,      // [B*N] packed (x,y,z,s2)  (PACKED)
    const float* __restrict__ xyz_raw,   // [B*N, 3]                 (!PACKED)
    const float4* __restrict__ feat4,    // [B*N, 64]  (C=256)
    float4* __restrict__ out4,           // [B*M, 64]
    int N, int blocks_per_batch)
{
    __shared__ float s_d[SPLIT][QPB][3];
    __shared__ int   s_i[SPLIT][QPB][3];
    __shared__ float s_w[QPB][3];
    __shared__ int   s_j[QPB][3];

    int g = blockIdx.x;
    // XCD swizzle (bijective for 1024 blocks): batch b's 256 blocks land on
    // XCD pair {2b,2b+1} so its 4 MiB feat slab fits that XCD's L2.
    if (gridDim.x == 1024 && blocks_per_batch == 256) {
        const int xcd = g & 7, slot = g >> 3;
        g = (xcd >> 1) * 256 + (xcd & 1) * 128 + slot;
    }

    const int tid = threadIdx.x;
    const int q   = tid & 63;    // query within block
    const int s   = tid >> 6;    // chunk id == wave id (wave-uniform)
    const int b   = g / blocks_per_batch;
    const int src_base = b * N;
    const int m = g * QPB + q;   // global query index

    const float qx = new_xyz[(size_t)m * 3 + 0];
    const float qy = new_xyz[(size_t)m * 3 + 1];
    const float qz = new_xyz[(size_t)m * 3 + 2];
    const float q2 = __fadd_rn(__fadd_rn(__fmul_rn(qx, qx), __fmul_rn(qy, qy)),
                               __fmul_rn(qz, qz));

    const int chunk = N / SPLIT;
    const int cbase = s * chunk;

    float b0 = FLT_MAX, b1 = FLT_MAX, b2 = FLT_MAX;
    int   i0 = 0, i1 = 0, i2 = 0;

    if (PACKED) {
        const float4* __restrict__ cp = pts + src_base + cbase;
        #pragma unroll 8
        for (int j = 0; j < chunk; ++j) {
            const float4 p = cp[j];  // wave-uniform addr -> 1 L2 line/wave
            const float cross = __fadd_rn(
                __fadd_rn(__fmul_rn(qx, p.x), __fmul_rn(qy, p.y)),
                __fmul_rn(qz, p.z));
            const float d2 = __fadd_rn(q2, p.w) - (cross + cross);
            const int cj = cbase + j;
            const bool c0 = d2 < b0, c1 = d2 < b1, c2 = d2 < b2;
            const int ni0 = c0 ? cj : i0;
            const int ni1 = c0 ? i0 : (c1 ? cj : i1);
            const int ni2 = c1 ? i1 : (c2 ? cj : i2);
            const float nb0 = fminf(d2, b0);
            const float nb1 = __builtin_amdgcn_fmed3f(d2, b0, b1);
            const float nb2 = __builtin_amdgcn_fmed3f(d2, b1, b2);
            b0 = nb0; b1 = nb1; b2 = nb2;
            i0 = ni0; i1 = ni1; i2 = ni2;
        }
    } else {
        const float* __restrict__ cp = xyz_raw + (size_t)(src_base + cbase) * 3;
        #pragma unroll 4
        for (int j = 0; j < chunk; ++j) {
            const float sx = cp[(size_t)j * 3 + 0];
            const float sy = cp[(size_t)j * 3 + 1];
            const float sz = cp[(size_t)j * 3 + 2];
            const float s2 = __fadd_rn(
                __fadd_rn(__fmul_rn(sx, sx), __fmul_rn(sy, sy)),
                __fmul_rn(sz, sz));
            const float cross = __fadd_rn(
                __fadd_rn(__fmul_rn(qx, sx), __fmul_rn(qy, sy)),
                __fmul_rn(qz, sz));
            const float d2 = __fadd_rn(q2, s2) - (cross + cross);
            const int cj = cbase + j;
            const bool c0 = d2 < b0, c1 = d2 < b1, c2 = d2 < b2;
            const int ni0 = c0 ? cj : i0;
            const int ni1 = c0 ? i0 : (c1 ? cj : i1);
            const int ni2 = c1 ? i1 : (c2 ? cj : i2);
            const float nb0 = fminf(d2, b0);
            const float nb1 = __builtin_amdgcn_fmed3f(d2, b0, b1);
            const float nb2 = __builtin_amdgcn_fmed3f(d2, b1, b2);
            b0 = nb0; b1 = nb1; b2 = nb2;
            i0 = ni0; i1 = ni1; i2 = ni2;
        }
    }

    s_d[s][q][0] = b0; s_d[s][q][1] = b1; s_d[s][q][2] = b2;
    s_i[s][q][0] = i0; s_i[s][q][1] = i1; s_i[s][q][2] = i2;
    __syncthreads();

    // ---- 12-way tie-aware merge, one thread per query ----
    if (tid < QPB) {
        float m0 = FLT_MAX, m1 = FLT_MAX, m2 = FLT_MAX;
        int   j0 = 0, j1 = 0, j2 = 0;
        #pragma unroll
        for (int ss = 0; ss < SPLIT; ++ss) {
            #pragma unroll
            for (int r = 0; r < 3; ++r) {
                const float d = s_d[ss][tid][r];
                const int   i = s_i[ss][tid][r];
                const bool L0 = (d < m0) || (d == m0 && i < j0);
                const bool L1 = (d < m1) || (d == m1 && i < j1);
                const bool L2 = (d < m2) || (d == m2 && i < j2);
                const float n0 = L0 ? d : m0;
                const float n1 = L0 ? m0 : (L1 ? d : m1);
                const float n2 = L1 ? m1 : (L2 ? d : m2);
                const int   t0 = L0 ? i : j0;
                const int   t1 = L0 ? j0 : (L1 ? i : j1);
                const int   t2 = L1 ? j1 : (L2 ? i : j2);
                m0 = n0; m1 = n1; m2 = n2;
                j0 = t0; j1 = t1; j2 = t2;
            }
        }
        const float e0 = sqrtf(fmaxf(m0, 1e-12f));
        const float e1 = sqrtf(fmaxf(m1, 1e-12f));
        const float e2 = sqrtf(fmaxf(m2, 1e-12f));
        const float r0 = 1.0f / (e0 + 1e-8f);
        const float r1 = 1.0f / (e1 + 1e-8f);
        const float r2 = 1.0f / (e2 + 1e-8f);
        const float rs = r0 + r1 + r2;
        s_w[tid][0] = r0 / rs; s_w[tid][1] = r1 / rs; s_w[tid][2] = r2 / rs;
        s_j[tid][0] = j0;      s_j[tid][1] = j1;      s_j[tid][2] = j2;
    }
    __syncthreads();

    // ---- phase B: gather + interpolate; wave w handles 16 queries ----
    const int lane  = tid & 63;
    const int wv    = tid >> 6;
    const int qbase = g * QPB;
    #pragma unroll 2
    for (int t = 0; t < QPB / SPLIT; ++t) {
        const int qq = wv * (QPB / SPLIT) + t;
        const int   a0 = s_j[qq][0], a1 = s_j[qq][1], a2 = s_j[qq][2];
        const float u0 = s_w[qq][0], u1 = s_w[qq][1], u2 = s_w[qq][2];
        const float4 f0 = feat4[(size_t)(src_base + a0) * 64 + lane];
        const float4 f1 = feat4[(size_t)(src_base + a1) * 64 + lane];
        const float4 f2 = feat4[(size_t)(src_base + a2) * 64 + lane];
        float4 o;
        o.x = u0 * f0.x + u1 * f1.x + u2 * f2.x;
        o.y = u0 * f0.y + u1 * f1.y + u2 * f2.y;
        o.z = u0 * f0.z + u1 * f1.z + u2 * f2.z;
        o.w = u0 * f0.w + u1 * f1.w + u2 * f2.w;
        out4[(size_t)(qbase + qq) * 64 + lane] = o;
    }
}

extern "C" void kernel_launch(void* const* d_in, const int* in_sizes, int n_in,
                              void* d_out, int out_size, void* d_ws, size_t ws_size,
                              hipStream_t stream) {
    const float* xyz     = (const float*)d_in[0];
    const float* new_xyz = (const float*)d_in[1];
    const float* feat    = (const float*)d_in[2];
    float* out = (float*)d_out;

    const int B = in_sizes[3];                 // 4
    const int N = in_sizes[0] / (3 * B);       // 4096
    const int M = in_sizes[1] / (3 * B);       // 16384
    const int blocks = (B * M) / QPB;          // 1024
    const int bpb = M / QPB;                   // 256

    const size_t need = (size_t)(B * N) * sizeof(float4);  // 256 KiB
    if (ws_size >= need) {
        pack_pts<<<(B * N + 255) / 256, 256, 0, stream>>>(xyz, (float4*)d_ws, B * N);
        fp_knn_main<true><<<blocks, 256, 0, stream>>>(
            new_xyz, (const float4*)d_ws, nullptr,
            (const float4*)feat, (float4*)out, N, bpb);
    } else {
        fp_knn_main<false><<<blocks, 256, 0, stream>>>(
            new_xyz, nullptr, xyz,
            (const float4*)feat, (float4*)out, N, bpb);
    }
}

// Round 3
// 234.905 us; speedup vs baseline: 2.0422x; 1.1181x over previous
//
#include <hip/hip_runtime.h>
#include <float.h>

// FeatPropagation k=3 NN interpolation, round 3.
// R2 post-mortem: VALU-issue-bound (VALUBusy 79%), occupancy capped at 50%
// (4 blocks/CU), select chain ~2x costlier than modeled.
// R3: (a) grid 2048 (32 queries x 8 chunks per 256-thr block) -> 32 waves/CU;
//     (b) top-3 select on packed f64 keys: key = bits(d2)<<32 | idx, double
//         compare == exact (d2, idx) lexicographic order (positive d2), so
//         insert = 5 v_min/max_f64, no cmp/cndmask chains, no merge tie logic.
// Exactness contract unchanged: d2 = (q2+s2) - 2*((qx*sx+qy*sy)+qz*sz) with
// __fmul_rn/__fadd_rn per-op rounding; ties -> lower index (key low word).

#define QPB   32   // queries per block
#define SPLIT 8    // candidate chunks per block
#define KEY_INIT 0x7FEFFFFFFFFFFFFFULL  // DBL_MAX bits > any real key

__global__ void pack_pts(const float* __restrict__ xyz,
                         float4* __restrict__ pts, int total) {
    int i = blockIdx.x * blockDim.x + threadIdx.x;
    if (i < total) {
        const float sx = xyz[(size_t)i * 3 + 0];
        const float sy = xyz[(size_t)i * 3 + 1];
        const float sz = xyz[(size_t)i * 3 + 2];
        const float s2 = __fadd_rn(__fadd_rn(__fmul_rn(sx, sx), __fmul_rn(sy, sy)),
                                   __fmul_rn(sz, sz));
        pts[i] = make_float4(sx, sy, sz, s2);
    }
}

__device__ __forceinline__ double mk_key(float d2, int j) {
    unsigned long long u =
        ((unsigned long long)(unsigned)__float_as_uint(d2) << 32) | (unsigned)j;
    return __longlong_as_double(u);
}

template <int CHUNK>
__global__ __launch_bounds__(256, 8) void fp_knn_main(
    const float* __restrict__ new_xyz,   // [B*M, 3]
    const float4* __restrict__ pts,      // [B*N] packed (x,y,z,s2)
    const float4* __restrict__ feat4,    // [B*N, 64]  (C=256)
    float4* __restrict__ out4,           // [B*M, 64]
    int N, int blocks_per_batch)
{
    __shared__ double s_k[SPLIT][QPB][3];   // 6 KiB
    __shared__ float  s_w[QPB][3];
    __shared__ int    s_j[QPB][3];

    int g = blockIdx.x;
    // XCD swizzle (bijective, grid 2048): batch b's 512 blocks -> XCDs {2b,2b+1}
    // so its 4 MiB feat slab stays in one XCD pair's L2.
    if (gridDim.x == 2048 && blocks_per_batch == 512) {
        const int xcd = g & 7, slot = g >> 3;        // slot in [0,256)
        g = (xcd >> 1) * 512 + (xcd & 1) * 256 + slot;
    }

    const int tid = threadIdx.x;
    const int q   = tid & (QPB - 1);   // query within block
    const int s   = tid >> 5;          // chunk id, 0..7
    const int b   = g / blocks_per_batch;
    const int src_base = b * N;
    const int m = g * QPB + q;         // global query index

    const float qx = new_xyz[(size_t)m * 3 + 0];
    const float qy = new_xyz[(size_t)m * 3 + 1];
    const float qz = new_xyz[(size_t)m * 3 + 2];
    const float q2 = __fadd_rn(__fadd_rn(__fmul_rn(qx, qx), __fmul_rn(qy, qy)),
                               __fmul_rn(qz, qz));

    const int cbase = s * CHUNK;
    const float4* __restrict__ cp = pts + src_base + cbase;

    double k0 = __longlong_as_double(KEY_INIT);
    double k1 = k0, k2 = k0;

    #pragma unroll 8
    for (int j = 0; j < CHUNK; ++j) {
        const float4 p = cp[j];        // half-wave-uniform addr: 2 lines/wave
        const float cross = __fadd_rn(
            __fadd_rn(__fmul_rn(qx, p.x), __fmul_rn(qy, p.y)),
            __fmul_rn(qz, p.z));
        const float d2 = __fadd_rn(q2, p.w) - (cross + cross);
        const double key = mk_key(d2, cbase + j);
        const double n0 = fmin(key, k0);
        const double n1 = fmin(fmax(key, k0), k1);
        const double n2 = fmin(fmax(key, k1), k2);
        k0 = n0; k1 = n1; k2 = n2;
    }

    s_k[s][q][0] = k0; s_k[s][q][1] = k1; s_k[s][q][2] = k2;
    __syncthreads();

    // ---- 24-way merge per query (keys make it tie-exact for free) ----
    if (tid < QPB) {
        double m0 = __longlong_as_double(KEY_INIT), m1 = m0, m2 = m0;
        #pragma unroll
        for (int ss = 0; ss < SPLIT; ++ss) {
            #pragma unroll
            for (int r = 0; r < 3; ++r) {
                const double d = s_k[ss][tid][r];
                const double n0 = fmin(d, m0);
                const double n1 = fmin(fmax(d, m0), m1);
                const double n2 = fmin(fmax(d, m1), m2);
                m0 = n0; m1 = n1; m2 = n2;
            }
        }
        unsigned long long u0 = __double_as_longlong(m0);
        unsigned long long u1 = __double_as_longlong(m1);
        unsigned long long u2 = __double_as_longlong(m2);
        const float d0 = __uint_as_float((unsigned)(u0 >> 32));
        const float d1 = __uint_as_float((unsigned)(u1 >> 32));
        const float d2 = __uint_as_float((unsigned)(u2 >> 32));
        const float e0 = sqrtf(fmaxf(d0, 1e-12f));
        const float e1 = sqrtf(fmaxf(d1, 1e-12f));
        const float e2 = sqrtf(fmaxf(d2, 1e-12f));
        const float r0 = 1.0f / (e0 + 1e-8f);
        const float r1 = 1.0f / (e1 + 1e-8f);
        const float r2 = 1.0f / (e2 + 1e-8f);
        const float rs = r0 + r1 + r2;
        s_w[tid][0] = r0 / rs; s_w[tid][1] = r1 / rs; s_w[tid][2] = r2 / rs;
        s_j[tid][0] = (int)(u0 & 0xffffffffu);
        s_j[tid][1] = (int)(u1 & 0xffffffffu);
        s_j[tid][2] = (int)(u2 & 0xffffffffu);
    }
    __syncthreads();

    // ---- phase B: gather + interpolate; wave wv handles 8 queries ----
    const int lane  = tid & 63;
    const int wv    = tid >> 6;
    const int qbase = g * QPB;
    #pragma unroll 2
    for (int t = 0; t < QPB / 4; ++t) {
        const int qq = wv * (QPB / 4) + t;
        const int   a0 = s_j[qq][0], a1 = s_j[qq][1], a2 = s_j[qq][2];
        const float u0 = s_w[qq][0], u1 = s_w[qq][1], u2 = s_w[qq][2];
        const float4 f0 = feat4[(size_t)(src_base + a0) * 64 + lane];
        const float4 f1 = feat4[(size_t)(src_base + a1) * 64 + lane];
        const float4 f2 = feat4[(size_t)(src_base + a2) * 64 + lane];
        float4 o;
        o.x = u0 * f0.x + u1 * f1.x + u2 * f2.x;
        o.y = u0 * f0.y + u1 * f1.y + u2 * f2.y;
        o.z = u0 * f0.z + u1 * f1.z + u2 * f2.z;
        o.w = u0 * f0.w + u1 * f1.w + u2 * f2.w;
        out4[(size_t)(qbase + qq) * 64 + lane] = o;
    }
}

// Generic-chunk fallback (N not divisible as expected) — same semantics.
__global__ void fp_knn_generic(
    const float* __restrict__ new_xyz, const float* __restrict__ xyz,
    const float* __restrict__ feat, float* __restrict__ out,
    int N, int M, int Btot)
{
    const int m = blockIdx.x * blockDim.x + threadIdx.x;
    if (m >= Btot * M) return;
    const int b = m / M;
    const int src_base = b * N;
    const float qx = new_xyz[(size_t)m * 3 + 0];
    const float qy = new_xyz[(size_t)m * 3 + 1];
    const float qz = new_xyz[(size_t)m * 3 + 2];
    const float q2 = __fadd_rn(__fadd_rn(__fmul_rn(qx, qx), __fmul_rn(qy, qy)),
                               __fmul_rn(qz, qz));
    double k0 = __longlong_as_double(KEY_INIT), k1 = k0, k2 = k0;
    for (int j = 0; j < N; ++j) {
        const float sx = xyz[(size_t)(src_base + j) * 3 + 0];
        const float sy = xyz[(size_t)(src_base + j) * 3 + 1];
        const float sz = xyz[(size_t)(src_base + j) * 3 + 2];
        const float s2 = __fadd_rn(__fadd_rn(__fmul_rn(sx, sx), __fmul_rn(sy, sy)),
                                   __fmul_rn(sz, sz));
        const float cross = __fadd_rn(
            __fadd_rn(__fmul_rn(qx, sx), __fmul_rn(qy, sy)), __fmul_rn(qz, sz));
        const float d2 = __fadd_rn(q2, s2) - (cross + cross);
        const double key = mk_key(d2, j);
        const double n0 = fmin(key, k0);
        const double n1 = fmin(fmax(key, k0), k1);
        const double n2 = fmin(fmax(key, k1), k2);
        k0 = n0; k1 = n1; k2 = n2;
    }
    unsigned long long u0 = __double_as_longlong(k0);
    unsigned long long u1 = __double_as_longlong(k1);
    unsigned long long u2 = __double_as_longlong(k2);
    const float e0 = sqrtf(fmaxf(__uint_as_float((unsigned)(u0 >> 32)), 1e-12f));
    const float e1 = sqrtf(fmaxf(__uint_as_float((unsigned)(u1 >> 32)), 1e-12f));
    const float e2 = sqrtf(fmaxf(__uint_as_float((unsigned)(u2 >> 32)), 1e-12f));
    const float r0 = 1.0f / (e0 + 1e-8f);
    const float r1 = 1.0f / (e1 + 1e-8f);
    const float r2 = 1.0f / (e2 + 1e-8f);
    const float rs = r0 + r1 + r2;
    const float w0 = r0 / rs, w1 = r1 / rs, w2 = r2 / rs;
    const int a0 = (int)(u0 & 0xffffffffu), a1 = (int)(u1 & 0xffffffffu),
              a2 = (int)(u2 & 0xffffffffu);
    const int C = 256;
    for (int c = 0; c < C; ++c) {
        out[(size_t)m * C + c] =
            w0 * feat[(size_t)(src_base + a0) * C + c] +
            w1 * feat[(size_t)(src_base + a1) * C + c] +
            w2 * feat[(size_t)(src_base + a2) * C + c];
    }
}

extern "C" void kernel_launch(void* const* d_in, const int* in_sizes, int n_in,
                              void* d_out, int out_size, void* d_ws, size_t ws_size,
                              hipStream_t stream) {
    const float* xyz     = (const float*)d_in[0];
    const float* new_xyz = (const float*)d_in[1];
    const float* feat    = (const float*)d_in[2];
    float* out = (float*)d_out;

    const int B = in_sizes[3];                 // 4
    const int N = in_sizes[0] / (3 * B);       // 4096
    const int M = in_sizes[1] / (3 * B);       // 16384

    const size_t need = (size_t)(B * N) * sizeof(float4);  // 256 KiB
    const bool fast = (N % SPLIT == 0) && (N / SPLIT == 512) &&
                      (M % QPB == 0) && (ws_size >= need);
    if (fast) {
        pack_pts<<<(B * N + 255) / 256, 256, 0, stream>>>(xyz, (float4*)d_ws, B * N);
        const int blocks = (B * M) / QPB;      // 2048
        fp_knn_main<512><<<blocks, 256, 0, stream>>>(
            new_xyz, (const float4*)d_ws, (const float4*)feat, (float4*)out,
            N, M / QPB);
    } else {
        fp_knn_generic<<<(B * M + 255) / 256, 256, 0, stream>>>(
            new_xyz, xyz, feat, out, N, M, B);
    }
}